// Round 1
// baseline (6609.483 us; speedup 1.0000x reference)
//
#include <hip/hip_runtime.h>

#define TPB 256

// ---------------------------------------------------------------- transpose x -> NHWC
__global__ __launch_bounds__(256) void k_transpose_x(const float* __restrict__ x,
                                                     float* __restrict__ xT){
  __shared__ float tile[64][65];
  const int y = blockIdx.x, b = blockIdx.y;
  for (int i = threadIdx.x; i < 4096; i += TPB){
    const int c = i >> 6, xx = i & 63;
    tile[c][xx] = x[b*262144 + c*4096 + y*64 + xx];
  }
  __syncthreads();
  for (int i = threadIdx.x; i < 4096; i += TPB){
    const int xx = i >> 6, c = i & 63;
    xT[(b*4096 + y*64 + xx)*64 + c] = tile[c][xx];
  }
}

// ---------------------------------------------------------------- aux conv weights -> [ch][k][c]
__global__ __launch_bounds__(256) void k_prep_waux(
    const float* __restrict__ off1w, const float* __restrict__ mod1w,
    const float* __restrict__ off2w, const float* __restrict__ mod2w,
    float* __restrict__ waux1, float* __restrict__ waux2){
  const int i = blockIdx.x*TPB + threadIdx.x;
  if (i < 27*9*64){
    const int c = i & 63, k = (i >> 6) % 9, ch = i / 576;
    waux1[i] = (ch < 18) ? off1w[(ch*64 + c)*9 + k] : mod1w[((ch-18)*64 + c)*9 + k];
  }
  if (i < 27*9*128){
    const int c = i & 127, k = (i >> 7) % 9, ch = i / 1152;
    waux2[i] = (ch < 18) ? off2w[(ch*128 + c)*9 + k] : mod2w[((ch-18)*128 + c)*9 + k];
  }
}

// ---------------------------------------------------------------- fused offset+mask 3x3 conv
// grid (64 ho, 16 b), 256 thr, dyn LDS = 3*64*68*4 = 52224 B
template<int CIN>
__global__ __launch_bounds__(256) void k_aux_conv(
    const float* __restrict__ inT, const float* __restrict__ wauxT,
    float* __restrict__ off_out, float* __restrict__ mask_out){
  extern __shared__ float xs[];  // [3][64][68]
  const int ho = blockIdx.x, b = blockIdx.y, tid = threadIdx.x;
  float acc[7];
  #pragma unroll
  for (int i = 0; i < 7; ++i) acc[i] = 0.f;
  for (int pass = 0; pass < CIN/64; ++pass){
    if (pass) __syncthreads();
    #pragma unroll
    for (int kh = 0; kh < 3; ++kh){
      const int y = ho - 1 + kh;
      const bool vy = (y >= 0) && (y < 64);
      for (int i = tid; i < 4096; i += TPB){
        const int wx = i >> 6, c = i & 63;
        xs[(kh*64 + wx)*68 + c] = vy ? inT[((b*64 + y)*64 + wx)*CIN + pass*64 + c] : 0.f;
      }
    }
    __syncthreads();
    for (int oi = 0; oi < 7; ++oi){
      const int idx = tid + oi*TPB;
      if (idx < 1728){
        const int ch = __builtin_amdgcn_readfirstlane(idx >> 6);  // wave-uniform
        const int wo = idx & 63;
        float a = acc[oi];
        #pragma unroll
        for (int kh = 0; kh < 3; ++kh){
          #pragma unroll
          for (int kw = 0; kw < 3; ++kw){
            const int wx = wo + kw - 1;
            if (wx >= 0 && wx < 64){
              const float* xp = &xs[(kh*64 + wx)*68];
              const float* wp = wauxT + (ch*9 + kh*3 + kw)*CIN + pass*64;
              #pragma unroll
              for (int c = 0; c < 64; c += 4){
                const float4 xv = *(const float4*)(xp + c);
                const float4 wv = *(const float4*)(wp + c);
                a = fmaf(xv.x, wv.x, a); a = fmaf(xv.y, wv.y, a);
                a = fmaf(xv.z, wv.z, a); a = fmaf(xv.w, wv.w, a);
              }
            }
          }
        }
        acc[oi] = a;
      }
    }
  }
  for (int oi = 0; oi < 7; ++oi){
    const int idx = tid + oi*TPB;
    if (idx < 1728){
      const int ch = idx >> 6, wo = idx & 63;
      if (ch < 18) off_out[((b*18 + ch)*64 + ho)*64 + wo] = acc[oi];
      else mask_out[((b*9 + ch - 18)*64 + ho)*64 + wo] = 1.f/(1.f + expf(-acc[oi]));
    }
  }
}

// ---------------------------------------------------------------- deformable conv
// grid (64 ho, 16 b), 256 thr.
// STAGE 1: out = out1T NHWC, fused BN+ReLU.  STAGE 2: out = partial[(b*64+ho)*128+co].
template<int CIN, int STAGE>
__global__ __launch_bounds__(256) void k_deform(
    const float* __restrict__ inT, const float* __restrict__ off,
    const float* __restrict__ mask, const float* __restrict__ wflat,
    const float* __restrict__ bng, const float* __restrict__ bnb,
    const float* __restrict__ bnm, const float* __restrict__ bnv,
    float* __restrict__ out){
  extern __shared__ float smem[];
  float* g = smem;                         // 16 * 580 floats (stride 580 ≡ 4 mod 32)
  int* o00 = (int*)(smem + 16*580);        // 144 each
  int* o01 = o00 + 144;
  int* o10 = o01 + 144;
  int* o11 = o10 + 144;
  float4* wm = (float4*)(o11 + 144);       // 144 float4 (mask-folded bilinear wts)
  float* aux = (float*)(wm + 144);         // stage1: inv[128]+bias[128]; stage2: red[128][17]
  const int JTOT = CIN*9;
  const int ho = blockIdx.x, b = blockIdx.y, tid = threadIdx.x;
  const int px = tid >> 4, cg = tid & 15, co0 = cg*8;
  const float* inb = inT + b*4096*CIN;
  float tot[8];
  #pragma unroll
  for (int r = 0; r < 8; ++r) tot[r] = 0.f;
  if (STAGE == 1 && tid < 128){
    const float inv = rsqrtf(bnv[tid] + 1e-5f)*bng[tid];
    aux[tid] = inv;
    aux[128 + tid] = bnb[tid] - bnm[tid]*inv;
  }
  for (int chunk = 0; chunk < 4; ++chunk){
    const int wo0 = chunk*16;
    __syncthreads();
    if (tid < 144){                        // phase 1a: sample params
      const int pl = tid/9, k = tid - pl*9;
      const int kh = k/3, kw = k - kh*3;
      const int wo = wo0 + pl;
      const int oidx = ((b*18 + 2*k)*64 + ho)*64 + wo;
      const float oy = off[oidx];
      const float ox = off[oidx + 4096];
      const float m  = mask[((b*9 + k)*64 + ho)*64 + wo];
      const float py  = (float)(ho - 1 + kh) + oy;
      const float pxf = (float)(wo - 1 + kw) + ox;
      const float fy = floorf(py), fx = floorf(pxf);
      const int y0 = (int)fy, x0 = (int)fx;
      const float dy = py - fy, dx = pxf - fx;
      const bool vy0 = (y0 >= 0) && (y0 < 64), vy1 = (y0 >= -1) && (y0 < 63);
      const bool vx0 = (x0 >= 0) && (x0 < 64), vx1 = (x0 >= -1) && (x0 < 63);
      const int y0c = min(max(y0, 0), 63), y1c = min(max(y0 + 1, 0), 63);
      const int x0c = min(max(x0, 0), 63), x1c = min(max(x0 + 1, 0), 63);
      o00[tid] = y0c*64 + x0c; o01[tid] = y0c*64 + x1c;
      o10[tid] = y1c*64 + x0c; o11[tid] = y1c*64 + x1c;
      wm[tid] = make_float4((1.f-dy)*(1.f-dx)*m*(vy0&&vx0 ? 1.f:0.f),
                            (1.f-dy)*dx*m*(vy0&&vx1 ? 1.f:0.f),
                            dy*(1.f-dx)*m*(vy1&&vx0 ? 1.f:0.f),
                            dy*dx*m*(vy1&&vx1 ? 1.f:0.f));
    }
    __syncthreads();
    float acc[8];
    #pragma unroll
    for (int r = 0; r < 8; ++r) acc[r] = 0.f;
    for (int pass = 0; pass < CIN/64; ++pass){
      if (pass) __syncthreads();
      {                                    // phase 1b: gather g (64-channel window)
        const int c = tid & 63;
        const int cc = pass*64 + c;
        const int pl0 = tid >> 6;
        #pragma unroll
        for (int it = 0; it < 4; ++it){
          const int pl = pl0 + it*4;
          #pragma unroll
          for (int k = 0; k < 9; ++k){
            const int p = pl*9 + k;
            const float4 w4 = wm[p];
            const float v = w4.x*inb[o00[p]*CIN + cc] + w4.y*inb[o01[p]*CIN + cc]
                          + w4.z*inb[o10[p]*CIN + cc] + w4.w*inb[o11[p]*CIN + cc];
            g[pl*580 + c*9 + k] = v;
          }
        }
      }
      __syncthreads();
      const float* wp = wflat + co0*JTOT + pass*576;   // phase 2: (px, 8 couts) dots
      const float* gp = g + px*580;
      #pragma unroll 2
      for (int j = 0; j < 576; j += 4){
        const float4 g4 = *(const float4*)(gp + j);
        #pragma unroll
        for (int r = 0; r < 8; ++r){
          const float4 w4 = *(const float4*)(wp + r*JTOT + j);
          acc[r] = fmaf(g4.x, w4.x, acc[r]); acc[r] = fmaf(g4.y, w4.y, acc[r]);
          acc[r] = fmaf(g4.z, w4.z, acc[r]); acc[r] = fmaf(g4.w, w4.w, acc[r]);
        }
      }
    }
    if (STAGE == 1){
      const int wo = wo0 + px;
      const int obase = ((b*64 + ho)*64 + wo)*128 + co0;
      #pragma unroll
      for (int r = 0; r < 8; ++r){
        const float v = acc[r]*aux[co0 + r] + aux[128 + co0 + r];
        out[obase + r] = v > 0.f ? v : 0.f;
      }
    } else {
      #pragma unroll
      for (int r = 0; r < 8; ++r) tot[r] += acc[r];
    }
  }
  if (STAGE == 2){
    __syncthreads();
    #pragma unroll
    for (int r = 0; r < 8; ++r) aux[(co0 + r)*17 + px] = tot[r];
    __syncthreads();
    if (tid < 128){
      float s = 0.f;
      #pragma unroll
      for (int p = 0; p < 16; ++p) s += aux[tid*17 + p];
      out[(b*64 + ho)*128 + tid] = s;
    }
  }
}

// ---------------------------------------------------------------- pool + BN2 fold
__global__ __launch_bounds__(256) void k_pool(
    const float* __restrict__ partial,
    const float* __restrict__ g2, const float* __restrict__ b2,
    const float* __restrict__ m2, const float* __restrict__ v2,
    float* __restrict__ pooled){
  const int t = blockIdx.x*TPB + threadIdx.x;
  if (t >= 2048) return;
  const int b = t >> 7, c = t & 127;
  float s = 0.f;
  for (int h = 0; h < 64; ++h) s += partial[(b*64 + h)*128 + c];
  const float inv = rsqrtf(v2[c] + 1e-5f)*g2[c];
  pooled[t] = s*(1.f/4096.f)*inv + (b2[c] - m2[c]*inv);
}

// ---------------------------------------------------------------- fc
__global__ __launch_bounds__(256) void k_fc(
    const float* __restrict__ pooled, const float* __restrict__ fcw,
    const float* __restrict__ fcb, float* __restrict__ outp){
  const int t = blockIdx.x*TPB + threadIdx.x;
  if (t >= 16000) return;
  const int b = t/1000, n = t - b*1000;
  const float* p = pooled + b*128;
  const float* w = fcw + n*128;
  float s = fcb[n];
  #pragma unroll
  for (int c = 0; c < 128; c += 4){
    const float4 pv = *(const float4*)(p + c);
    const float4 wv = *(const float4*)(w + c);
    s = fmaf(pv.x, wv.x, s); s = fmaf(pv.y, wv.y, s);
    s = fmaf(pv.z, wv.z, s); s = fmaf(pv.w, wv.w, s);
  }
  outp[t] = s;
}

extern "C" void kernel_launch(void* const* d_in, const int* in_sizes, int n_in,
                              void* d_out, int out_size, void* d_ws, size_t ws_size,
                              hipStream_t stream){
  const float* x      = (const float*)d_in[0];
  const float* conv1w = (const float*)d_in[1];
  const float* off1w  = (const float*)d_in[2];
  const float* mod1w  = (const float*)d_in[3];
  const float* bn1g   = (const float*)d_in[4];
  const float* bn1b   = (const float*)d_in[5];
  const float* bn1m   = (const float*)d_in[6];
  const float* bn1v   = (const float*)d_in[7];
  const float* conv2w = (const float*)d_in[8];
  const float* off2w  = (const float*)d_in[9];
  const float* mod2w  = (const float*)d_in[10];
  const float* bn2g   = (const float*)d_in[11];
  const float* bn2b   = (const float*)d_in[12];
  const float* bn2m   = (const float*)d_in[13];
  const float* bn2v   = (const float*)d_in[14];
  const float* fcw    = (const float*)d_in[15];
  const float* fcb    = (const float*)d_in[16];

  float* ws      = (float*)d_ws;
  float* xT      = ws;                     // 16*64*64*64   = 4194304
  float* off1    = xT      + 4194304;      // 16*18*64*64   = 1179648
  float* mask1   = off1    + 1179648;      // 16*9*64*64    =  589824
  float* out1T   = mask1   + 589824;       // 16*64*64*128  = 8388608
  float* off2    = out1T   + 8388608;      // 1179648
  float* mask2   = off2    + 1179648;      // 589824
  float* partial = mask2   + 589824;       // 1024*128      =  131072
  float* pooled  = partial + 131072;       // 2048
  float* waux1   = pooled  + 2048;         // 27*9*64       =   15552
  float* waux2   = waux1   + 15552;        // 27*9*128      =   31104

  const dim3 gBH(64, 16);
  k_transpose_x<<<gBH, TPB, 0, stream>>>(x, xT);
  k_prep_waux<<<(27*9*128 + TPB - 1)/TPB, TPB, 0, stream>>>(off1w, mod1w, off2w, mod2w, waux1, waux2);
  k_aux_conv<64><<<gBH, TPB, 3*64*68*4, stream>>>(xT, waux1, off1, mask1);
  k_deform<64,1><<<gBH, TPB, (16*580 + 576 + 576 + 256)*4, stream>>>(
      xT, off1, mask1, conv1w, bn1g, bn1b, bn1m, bn1v, out1T);
  k_aux_conv<128><<<gBH, TPB, 3*64*68*4, stream>>>(out1T, waux2, off2, mask2);
  k_deform<128,2><<<gBH, TPB, (16*580 + 576 + 576 + 128*17)*4, stream>>>(
      out1T, off2, mask2, conv2w, nullptr, nullptr, nullptr, nullptr, partial);
  k_pool<<<8, TPB, 0, stream>>>(partial, bn2g, bn2b, bn2m, bn2v, pooled);
  k_fc<<<(16000 + TPB - 1)/TPB, TPB, 0, stream>>>(pooled, fcw, fcb, (float*)d_out);
}

// Round 4
// 250.090 us; speedup vs baseline: 26.4284x; 26.4284x over previous
//
#include <hip/hip_runtime.h>
#include <hip/hip_bf16.h>

#define TPB 256
typedef unsigned short us;
typedef __attribute__((ext_vector_type(8))) short bf16x8;
typedef __attribute__((ext_vector_type(4))) float f32x4;

__device__ inline us f2bf(float f){
  union{ __hip_bfloat16 h; us s; } x; x.h = __float2bfloat16(f); return x.s;
}
__device__ inline float bf2f(us u){ union{unsigned v; float f;} x; x.v = ((unsigned)u)<<16; return x.f; }
__device__ inline void split2(float v, us& hi, us& lo){
  hi = f2bf(v);
  lo = f2bf(v - bf2f(hi));
}

// ---------------------------------------------------------------- x NCHW f32 -> NHWC f32
__global__ __launch_bounds__(256) void k_transpose_x(const float* __restrict__ x,
                                                     float* __restrict__ xT){
  __shared__ float tile[64][65];
  const int y = blockIdx.x, b = blockIdx.y;
  for (int i = threadIdx.x; i < 4096; i += TPB){
    const int c = i >> 6, xx = i & 63;
    tile[c][xx] = x[b*262144 + c*4096 + y*64 + xx];
  }
  __syncthreads();
  for (int i = threadIdx.x; i < 4096; i += TPB){
    const int xx = i >> 6, c = i & 63;
    xT[(size_t)(b*4096 + y*64 + xx)*64 + c] = tile[c][xx];
  }
}

// ---------------------------------------------------------------- weights -> fragment-linear split-bf16
// per table: [k(9)][plane(2: hi,lo)][kb][n0][lane(64)][j(8)]
// elem = W[co = n0*16+(l&15)][c = kb*32+(l>>4)*8+j][k]
// plane offset within a k: r = (kb*NT + n0)*512 + l*8 + j
__global__ __launch_bounds__(256) void k_prep(
    const float* __restrict__ cw1, const float* __restrict__ ow1, const float* __restrict__ mw1,
    const float* __restrict__ cw2, const float* __restrict__ ow2, const float* __restrict__ mw2,
    us* __restrict__ d1, us* __restrict__ d2, us* __restrict__ a1, us* __restrict__ a2){
  const int e = blockIdx.x*TPB + threadIdx.x;
  { // deform1: CIN=64, NT=8, KB=2, WELEM=8192, total 9*2*8192=147456
    if (e < 147456){
      int k = e/16384, plane = (e%16384)/8192, r = e%8192;
      int kb = r/4096, r2 = r%4096;
      int n0 = r2>>9, q = r2&511, l = q>>3, j = q&7;
      int co = n0*16 + (l&15), c = kb*32 + (l>>4)*8 + j;
      float w = cw1[(co*64 + c)*9 + k];
      us hi, lo; split2(w, hi, lo);
      d1[e] = plane ? lo : hi;
    }
  }
  { // deform2: CIN=128, NT=8, KB=4, WELEM=16384, total 294912
    if (e < 294912){
      int k = e/32768, plane = (e%32768)/16384, r = e%16384;
      int kb = r/4096, r2 = r%4096;
      int n0 = r2>>9, q = r2&511, l = q>>3, j = q&7;
      int co = n0*16 + (l&15), c = kb*32 + (l>>4)*8 + j;
      float w = cw2[(co*128 + c)*9 + k];
      us hi, lo; split2(w, hi, lo);
      d2[e] = plane ? lo : hi;
    }
  }
  { // aux1: CIN=64, NT=2, KB=2, WELEM=2048, total 36864
    if (e < 36864){
      int k = e/4096, plane = (e%4096)/2048, r = e%2048;
      int kb = r/1024, r2 = r%1024;
      int n0 = r2>>9, q = r2&511, l = q>>3, j = q&7;
      int co = n0*16 + (l&15), c = kb*32 + (l>>4)*8 + j;
      float w = (co < 18) ? ow1[(co*64 + c)*9 + k] : (co < 27 ? mw1[((co-18)*64 + c)*9 + k] : 0.f);
      us hi, lo; split2(w, hi, lo);
      a1[e] = plane ? lo : hi;
    }
  }
  { // aux2: CIN=128, NT=2, KB=4, WELEM=4096, total 73728
    if (e < 73728){
      int k = e/8192, plane = (e%8192)/4096, r = e%4096;
      int kb = r/1024, r2 = r%1024;            // FIX: was r/2048 / %2048 (scrambled stage-2 aux weights)
      int n0 = r2>>9, q = r2&511, l = q>>3, j = q&7;
      int co = n0*16 + (l&15), c = kb*32 + (l>>4)*8 + j;
      float w = (co < 18) ? ow2[(co*128 + c)*9 + k] : (co < 27 ? mw2[((co-18)*128 + c)*9 + k] : 0.f);
      us hi, lo; split2(w, hi, lo);
      a2[e] = plane ? lo : hi;
    }
  }
}

// ---------------------------------------------------------------- unified (deformable) conv, split-bf16 MFMA
// MODE 0: aux conv (COUT=32, integer taps, unit mask) -> off / sigmoid-mask
// MODE 1: deform stage1 -> BN+ReLU -> f32 NHWC out
// MODE 2: deform stage2 -> per-(b,ho) column sums
template<int CIN, int COUT, int MODE>
__global__ __launch_bounds__(256) void k_conv(
    const float* __restrict__ inT, const float* __restrict__ off, const float* __restrict__ mask,
    const us* __restrict__ wb,
    const float* __restrict__ q0, const float* __restrict__ q1,
    const float* __restrict__ q2, const float* __restrict__ q3,
    float* __restrict__ outA, float* __restrict__ outB, float* __restrict__ outT){
  constexpr int GSTR = CIN + 8;
  constexpr int NT   = (COUT == 128) ? 8 : 2;
  constexpr int KB   = CIN/32;
  constexpr int WELEM = NT*KB*512;
  constexpr int NTW  = NT/2;
  extern __shared__ __align__(16) char smem[];
  us*     gh   = (us*)smem;                      // 64*GSTR (hi plane)
  us*     gl   = gh + 64*GSTR;                   // 64*GSTR (lo plane)
  uint2*  otab = (uint2*)(gl + 64*GSTR);         // 576
  float4* wtab = (float4*)(otab + 576);          // 576 (fp32 bilinear weights)
  float*  extra = (float*)(wtab + 576);          // MODE0: 32*66 ; MODE1/2: 256

  const int id  = blockIdx.x;
  const int nid = (id & 7)*128 + (id >> 3);      // XCD swizzle (1024 % 8 == 0, bijective)
  const int b = nid >> 6, ho = nid & 63;
  const int tid = threadIdx.x;
  const float* __restrict__ inb = inT + (size_t)b*4096*CIN;

  if (MODE == 1 && tid < 128){
    float inv = rsqrtf(q3[tid] + 1e-5f)*q0[tid];
    extra[tid] = inv; extra[128 + tid] = q1[tid] - q2[tid]*inv;
  }

  // ---- params: 576 samples (px, tap k)
  for (int it = 0; it < 3; ++it){
    int sid = it*256 + tid;
    if (sid < 576){
      int k = sid >> 6, px = sid & 63;
      int kh = k/3, kw = k - kh*3;
      if (MODE == 0){
        int y = ho - 1 + kh, x = px - 1 + kw;
        bool v = (y >= 0) && (y < 64) && (x >= 0) && (x < 64);
        int yc = min(max(y,0),63), xc = min(max(x,0),63);
        otab[sid] = make_uint2((unsigned)(yc*64 + xc), 0u);
        wtab[sid] = make_float4(v ? 1.f : 0.f, 0.f, 0.f, 0.f);
      } else {
        int oidx = ((b*18 + 2*k)*64 + ho)*64 + px;
        float oy = off[oidx], ox = off[oidx + 4096];
        float m  = mask[((b*9 + k)*64 + ho)*64 + px];
        float py = (float)(ho - 1 + kh) + oy;
        float pxx = (float)(px - 1 + kw) + ox;
        float fy = floorf(py), fx = floorf(pxx);
        int y0 = (int)fy, x0 = (int)fx;
        float dy = py - fy, dx = pxx - fx;
        bool vy0 = (y0 >= 0) && (y0 < 64), vy1 = (y0 >= -1) && (y0 < 63);
        bool vx0 = (x0 >= 0) && (x0 < 64), vx1 = (x0 >= -1) && (x0 < 63);
        int y0c = min(max(y0,0),63), y1c = min(max(y0+1,0),63);
        int x0c = min(max(x0,0),63), x1c = min(max(x0+1,0),63);
        unsigned o00 = y0c*64 + x0c, o01 = y0c*64 + x1c;
        unsigned o10 = y1c*64 + x0c, o11 = y1c*64 + x1c;
        otab[sid] = make_uint2(o00 | (o01 << 16), o10 | (o11 << 16));
        wtab[sid] = make_float4((1.f-dy)*(1.f-dx)*m*((vy0 && vx0) ? 1.f : 0.f),
                                (1.f-dy)*dx     *m*((vy0 && vx1) ? 1.f : 0.f),
                                dy*(1.f-dx)     *m*((vy1 && vx0) ? 1.f : 0.f),
                                dy*dx           *m*((vy1 && vx1) ? 1.f : 0.f));
      }
    }
  }
  __syncthreads();

  const int lane = tid & 63, lr = lane & 15, lg = lane >> 4;
  const int wv = tid >> 6, mh = wv & 1, nh = wv >> 1;
  f32x4 acc[2][NTW];
  #pragma unroll
  for (int m = 0; m < 2; ++m)
    #pragma unroll
    for (int n = 0; n < NTW; ++n) acc[m][n] = (f32x4){0.f,0.f,0.f,0.f};

  constexpr int CPG = CIN/4;       // lanes covering channels of one px
  constexpr int PXI = 256/CPG;     // px per gather iter
  constexpr int NIT = 64/PXI;
  const int c0  = (tid % CPG)*4;
  const int pxb = tid / CPG;

  for (int k = 0; k < 9; ++k){
    // ---- gather g[px][c] fp32 -> split bf16 hi/lo planes
    for (int it = 0; it < NIT; ++it){
      int px = it*PXI + pxb;
      uint2 op = otab[k*64 + px];
      float4 w4 = wtab[k*64 + px];
      float v0, v1, v2, v3;
      if (MODE == 0){
        if (w4.x != 0.f){
          float4 q = *(const float4*)(inb + (size_t)(op.x & 0xffffu)*CIN + c0);
          v0 = q.x; v1 = q.y; v2 = q.z; v3 = q.w;
        } else v0 = v1 = v2 = v3 = 0.f;
      } else {
        const float4 qa = *(const float4*)(inb + (size_t)(op.x & 0xffffu)*CIN + c0);
        const float4 qb = *(const float4*)(inb + (size_t)(op.x >> 16)    *CIN + c0);
        const float4 qc = *(const float4*)(inb + (size_t)(op.y & 0xffffu)*CIN + c0);
        const float4 qd = *(const float4*)(inb + (size_t)(op.y >> 16)    *CIN + c0);
        v0 = w4.x*qa.x + w4.y*qb.x + w4.z*qc.x + w4.w*qd.x;
        v1 = w4.x*qa.y + w4.y*qb.y + w4.z*qc.y + w4.w*qd.y;
        v2 = w4.x*qa.z + w4.y*qb.z + w4.z*qc.z + w4.w*qd.z;
        v3 = w4.x*qa.w + w4.y*qb.w + w4.z*qc.w + w4.w*qd.w;
      }
      us h0,l0,h1,l1,h2,l2,h3,l3;
      split2(v0,h0,l0); split2(v1,h1,l1); split2(v2,h2,l2); split2(v3,h3,l3);
      *(uint2*)(gh + px*GSTR + c0) = make_uint2((unsigned)h0 | ((unsigned)h1<<16),
                                                (unsigned)h2 | ((unsigned)h3<<16));
      *(uint2*)(gl + px*GSTR + c0) = make_uint2((unsigned)l0 | ((unsigned)l1<<16),
                                                (unsigned)l2 | ((unsigned)l3<<16));
    }
    __syncthreads();
    // ---- MFMA: acc += Ah*Bh + Al*Bh + Ah*Bl ; B streamed from global (coalesced, L2-hot)
    const us* wk = wb + (size_t)(k*2)*WELEM;
    #pragma unroll
    for (int kb = 0; kb < KB; ++kb){
      bf16x8 ah[2], al[2];
      ah[0] = *(const bf16x8*)(gh + (mh*32      + lr)*GSTR + kb*32 + lg*8);
      al[0] = *(const bf16x8*)(gl + (mh*32      + lr)*GSTR + kb*32 + lg*8);
      ah[1] = *(const bf16x8*)(gh + (mh*32 + 16 + lr)*GSTR + kb*32 + lg*8);
      al[1] = *(const bf16x8*)(gl + (mh*32 + 16 + lr)*GSTR + kb*32 + lg*8);
      #pragma unroll
      for (int nt = 0; nt < NTW; ++nt){
        int n0 = nh*NTW + nt;
        const us* bp = wk + (kb*NT + n0)*512 + lane*8;
        bf16x8 bh = *(const bf16x8*)bp;
        bf16x8 bl = *(const bf16x8*)(bp + WELEM);
        #pragma unroll
        for (int m = 0; m < 2; ++m){
          acc[m][nt] = __builtin_amdgcn_mfma_f32_16x16x32_bf16(ah[m], bh, acc[m][nt], 0, 0, 0);
          acc[m][nt] = __builtin_amdgcn_mfma_f32_16x16x32_bf16(al[m], bh, acc[m][nt], 0, 0, 0);
          acc[m][nt] = __builtin_amdgcn_mfma_f32_16x16x32_bf16(ah[m], bl, acc[m][nt], 0, 0, 0);
        }
      }
    }
    __syncthreads();   // protect g before next slice overwrites
  }

  // ---- epilogues
  if (MODE == 0){
    #pragma unroll
    for (int mt = 0; mt < 2; ++mt){
      int pxl = mh*32 + mt*16 + lg*4;
      int co = nh*16 + lr;
      #pragma unroll
      for (int i = 0; i < 4; ++i) extra[co*66 + pxl + i] = acc[mt][0][i];
    }
    __syncthreads();
    for (int idx = tid; idx < 27*64; idx += 256){
      int ch = idx >> 6, px = idx & 63;
      float v = extra[ch*66 + px];
      if (ch < 18) outA[((b*18 + ch)*64 + ho)*64 + px] = v;
      else         outB[((b*9 + ch - 18)*64 + ho)*64 + px] = 1.f/(1.f + expf(-v));
    }
  } else if (MODE == 1){
    const size_t rowbase = (size_t)(b*4096 + ho*64)*128;
    #pragma unroll
    for (int mt = 0; mt < 2; ++mt){
      int pxl = mh*32 + mt*16 + lg*4;
      #pragma unroll
      for (int nt = 0; nt < NTW; ++nt){
        int co = nh*64 + nt*16 + lr;
        float inv = extra[co], bia = extra[128 + co];
        #pragma unroll
        for (int i = 0; i < 4; ++i){
          float v = acc[mt][nt][i]*inv + bia;
          outT[rowbase + (size_t)(pxl + i)*128 + co] = fmaxf(v, 0.f);
        }
      }
    }
  } else {
    #pragma unroll
    for (int nt = 0; nt < NTW; ++nt){
      float s = acc[0][nt][0] + acc[0][nt][1] + acc[0][nt][2] + acc[0][nt][3]
              + acc[1][nt][0] + acc[1][nt][1] + acc[1][nt][2] + acc[1][nt][3];
      s += __shfl_xor(s, 16);
      s += __shfl_xor(s, 32);
      if (lane < 16) extra[mh*128 + nh*64 + nt*16 + lane] = s;
    }
    __syncthreads();
    if (tid < 128) outA[(size_t)(b*64 + ho)*128 + tid] = extra[tid] + extra[128 + tid];
  }
}

// ---------------------------------------------------------------- pool + BN2 fold
__global__ __launch_bounds__(256) void k_pool(
    const float* __restrict__ partial,
    const float* __restrict__ g2, const float* __restrict__ b2,
    const float* __restrict__ m2, const float* __restrict__ v2,
    float* __restrict__ pooled){
  const int t = blockIdx.x*TPB + threadIdx.x;
  if (t >= 2048) return;
  const int b = t >> 7, c = t & 127;
  float s = 0.f;
  for (int h = 0; h < 64; ++h) s += partial[(b*64 + h)*128 + c];
  const float inv = rsqrtf(v2[c] + 1e-5f)*g2[c];
  pooled[t] = s*(1.f/4096.f)*inv + (b2[c] - m2[c]*inv);
}

// ---------------------------------------------------------------- fc
__global__ __launch_bounds__(256) void k_fc(
    const float* __restrict__ pooled, const float* __restrict__ fcw,
    const float* __restrict__ fcb, float* __restrict__ outp){
  const int t = blockIdx.x*TPB + threadIdx.x;
  if (t >= 16000) return;
  const int b = t/1000, n = t - b*1000;
  const float* p = pooled + b*128;
  const float* w = fcw + n*128;
  float s = fcb[n];
  #pragma unroll
  for (int c = 0; c < 128; c += 4){
    const float4 pv = *(const float4*)(p + c);
    const float4 wv = *(const float4*)(w + c);
    s = fmaf(pv.x, wv.x, s); s = fmaf(pv.y, wv.y, s);
    s = fmaf(pv.z, wv.z, s); s = fmaf(pv.w, wv.w, s);
  }
  outp[t] = s;
}

extern "C" void kernel_launch(void* const* d_in, const int* in_sizes, int n_in,
                              void* d_out, int out_size, void* d_ws, size_t ws_size,
                              hipStream_t stream){
  const float* x      = (const float*)d_in[0];
  const float* conv1w = (const float*)d_in[1];
  const float* off1w  = (const float*)d_in[2];
  const float* mod1w  = (const float*)d_in[3];
  const float* bn1g   = (const float*)d_in[4];
  const float* bn1b   = (const float*)d_in[5];
  const float* bn1m   = (const float*)d_in[6];
  const float* bn1v   = (const float*)d_in[7];
  const float* conv2w = (const float*)d_in[8];
  const float* off2w  = (const float*)d_in[9];
  const float* mod2w  = (const float*)d_in[10];
  const float* bn2g   = (const float*)d_in[11];
  const float* bn2b   = (const float*)d_in[12];
  const float* bn2m   = (const float*)d_in[13];
  const float* bn2v   = (const float*)d_in[14];
  const float* fcw    = (const float*)d_in[15];
  const float* fcb    = (const float*)d_in[16];

  char* w = (char*)d_ws;
  float* xT      = (float*)(w);                   // 16,777,216 B
  float* out1T   = (float*)(w + 16777216);        // 33,554,432 B
  float* offb    = (float*)(w + 50331648);        //  4,718,592 B (stage1 then stage2)
  float* maskb   = (float*)(w + 55050240);        //  2,359,296 B (stage1 then stage2)
  float* partial = (float*)(w + 57409536);        //    524,288 B
  float* pooled  = (float*)(w + 57933824);        //      8,192 B
  us*    wb_d1   = (us*)(w + 57942016);           //    294,912 B
  us*    wb_d2   = (us*)(w + 58236928);           //    589,824 B
  us*    wb_a1   = (us*)(w + 58826752);           //     73,728 B
  us*    wb_a2   = (us*)(w + 58900480);           //    147,456 B

  k_transpose_x<<<dim3(64,16), TPB, 0, stream>>>(x, xT);
  k_prep<<<1152, TPB, 0, stream>>>(conv1w, off1w, mod1w, conv2w, off2w, mod2w,
                                   wb_d1, wb_d2, wb_a1, wb_a2);

  // LDS: 2*64*(CIN+8)*2 + 576*8 + 576*16 + extra*4
  const int lds_a1 = 18432 + 4608 + 9216 + 8448;  // 40704
  const int lds_d1 = 18432 + 4608 + 9216 + 1024;  // 33280
  const int lds_a2 = 34816 + 4608 + 9216 + 8448;  // 57088
  const int lds_d2 = 34816 + 4608 + 9216 + 1024;  // 49664

  k_conv<64,32,0><<<1024, TPB, lds_a1, stream>>>(
      xT, nullptr, nullptr, wb_a1, nullptr, nullptr, nullptr, nullptr,
      offb, maskb, nullptr);
  k_conv<64,128,1><<<1024, TPB, lds_d1, stream>>>(
      xT, offb, maskb, wb_d1, bn1g, bn1b, bn1m, bn1v,
      nullptr, nullptr, out1T);
  k_conv<128,32,0><<<1024, TPB, lds_a2, stream>>>(
      out1T, nullptr, nullptr, wb_a2, nullptr, nullptr, nullptr, nullptr,
      offb, maskb, nullptr);
  k_conv<128,128,2><<<1024, TPB, lds_d2, stream>>>(
      out1T, offb, maskb, wb_d2, nullptr, nullptr, nullptr, nullptr,
      partial, nullptr, nullptr);

  k_pool<<<8, TPB, 0, stream>>>(partial, bn2g, bn2b, bn2m, bn2v, pooled);
  k_fc<<<63, TPB, 0, stream>>>(pooled, fcw, fcb, (float*)d_out);
}